// Round 3
// baseline (559.535 us; speedup 1.0000x reference)
//
#include <hip/hip_runtime.h>
#include <hip/hip_bf16.h>
#include <cstdint>
#include <cstddef>

#define N 16384
#define DF 64

typedef __attribute__((ext_vector_type(8))) short short8;
typedef __attribute__((ext_vector_type(4))) float f32x4;

__device__ __forceinline__ unsigned short f2bf(float f) {
    union { float f; uint32_t u; } v; v.f = f;
    uint32_t u = v.u;
    uint32_t r = u + 0x7fffu + ((u >> 16) & 1u);  // RNE (data has no NaN/Inf)
    return (unsigned short)(r >> 16);
}

// ---------------- k1: partial column sums of A (race-free) ----------------
// grid (16, 64): blockIdx.x = 1024-col chunk, blockIdx.y = 256-row chunk
#define PROWS 64
__global__ __launch_bounds__(256) void colsum_kernel(const float* __restrict__ A,
                                                     float* __restrict__ partial) {
    int t = threadIdx.x;
    int c0 = blockIdx.x * 1024 + t * 4;
    int r0 = blockIdx.y * 256;
    const float* p = A + (size_t)r0 * N + c0;
    float ax = 0.f, ay = 0.f, az = 0.f, aw = 0.f;
    #pragma unroll 8
    for (int r = 0; r < 256; ++r) {
        float4 v = *(const float4*)(p + (size_t)r * N);
        ax += v.x; ay += v.y; az += v.z; aw += v.w;
    }
    float4 o; o.x = ax; o.y = ay; o.z = az; o.w = aw;
    *(float4*)&partial[(size_t)blockIdx.y * N + c0] = o;
}

// ---------------- k2: reduce partials -> d_inv + xs^T (bf16, [64][N]) ----------------
__global__ __launch_bounds__(256) void prep_kernel(const float* __restrict__ feat,
                                                   const float* __restrict__ partial,
                                                   float* __restrict__ d_inv,
                                                   unsigned short* __restrict__ xsT) {
    __shared__ float tile[64][68];
    int t = threadIdx.x;
    int i0 = blockIdx.x * 64;
    int r = t >> 2;
    int q = t & 3;
    float s = 0.f;
    #pragma unroll
    for (int p = 0; p < 16; ++p)
        s += partial[(size_t)(q * 16 + p) * N + i0 + r];
    s += __shfl_xor(s, 1);
    s += __shfl_xor(s, 2);
    float dinv = 1.0f / (s + 1.0f);
    if (q == 0) d_inv[i0 + r] = dinv;

    int cq = q * 16;
    const float* fp = feat + (size_t)(i0 + r) * DF + cq;
    #pragma unroll
    for (int j = 0; j < 16; j += 4) {
        float4 v = *(const float4*)(fp + j);
        tile[r][cq + j + 0] = v.x * dinv;
        tile[r][cq + j + 1] = v.y * dinv;
        tile[r][cq + j + 2] = v.z * dinv;
        tile[r][cq + j + 3] = v.w * dinv;
    }
    __syncthreads();
    int c = t >> 2;
    int iq = (t & 3) * 16;
    short8 b0, b1;
    #pragma unroll
    for (int j = 0; j < 8; ++j) b0[j] = (short)f2bf(tile[iq + j][c]);
    #pragma unroll
    for (int j = 0; j < 8; ++j) b1[j] = (short)f2bf(tile[iq + 8 + j][c]);
    unsigned short* dst = xsT + (size_t)c * N + i0 + iq;
    *(short8*)(dst) = b0;
    *(short8*)(dst + 8) = b1;
}

// ---------------- k3: slab[ks] = A[:, chunk] @ xs[chunk]  (bf16 MFMA, no LDS, no barriers) ----------------
#define KSPLIT 4
#define KCHUNK (N / KSPLIT)  // 4096

__global__ __launch_bounds__(256) void gemm_kernel(const float* __restrict__ A,
                                                   const unsigned short* __restrict__ xsT,
                                                   float* __restrict__ agg) {
    int t = threadIdx.x;
    int bid = blockIdx.x;
    int mb = bid >> 2;       // 0..255
    int ks = bid & 3;        // 0..3
    int m0 = mb * 64;
    int k0 = ks * KCHUNK;
    int w = t >> 6;          // wave 0..3 -> rows [m0+16w, +16)
    int l = t & 63;
    int row = m0 + w * 16 + (l & 15);
    int kofs = (l >> 4) * 8;

    const float* arow = A + (size_t)row * N + k0 + kofs;
    // B fragment base: col = ct*16 + (l&15), k = k0 + kk + kofs + j  (xsT is [col][N])
    const unsigned short* bp0 = xsT + (size_t)(l & 15) * N + k0 + kofs;
    const unsigned short* bp1 = bp0 + (size_t)16 * N;
    const unsigned short* bp2 = bp0 + (size_t)32 * N;
    const unsigned short* bp3 = bp0 + (size_t)48 * N;

    f32x4 acc[4] = {};
    #pragma unroll 2
    for (int kk = 0; kk < KCHUNK; kk += 32) {
        float4 a0 = *(const float4*)(arow + kk);
        float4 a1 = *(const float4*)(arow + kk + 4);
        short8 bf0 = *(const short8*)(bp0 + kk);
        short8 bf1 = *(const short8*)(bp1 + kk);
        short8 bf2 = *(const short8*)(bp2 + kk);
        short8 bf3 = *(const short8*)(bp3 + kk);
        short8 af;
        af[0] = (short)f2bf(a0.x); af[1] = (short)f2bf(a0.y);
        af[2] = (short)f2bf(a0.z); af[3] = (short)f2bf(a0.w);
        af[4] = (short)f2bf(a1.x); af[5] = (short)f2bf(a1.y);
        af[6] = (short)f2bf(a1.z); af[7] = (short)f2bf(a1.w);
        acc[0] = __builtin_amdgcn_mfma_f32_16x16x32_bf16(af, bf0, acc[0], 0, 0, 0);
        acc[1] = __builtin_amdgcn_mfma_f32_16x16x32_bf16(af, bf1, acc[1], 0, 0, 0);
        acc[2] = __builtin_amdgcn_mfma_f32_16x16x32_bf16(af, bf2, acc[2], 0, 0, 0);
        acc[3] = __builtin_amdgcn_mfma_f32_16x16x32_bf16(af, bf3, acc[3], 0, 0, 0);
    }
    // C/D layout: col = lane&15, row_in_tile = (lane>>4)*4 + reg
    float* slab = agg + (size_t)ks * N * DF;
    int crow = m0 + w * 16 + (l >> 4) * 4;
    int ccol = l & 15;
    #pragma unroll
    for (int ct = 0; ct < 4; ++ct) {
        #pragma unroll
        for (int q = 0; q < 4; ++q)
            slab[(size_t)(crow + q) * DF + ct * 16 + ccol] = acc[ct][q];
    }
}

// ---------------- k4: out = relu(((sum slabs + f*dinv)*dinv) @ W + bias) ----------------
__global__ __launch_bounds__(256) void epilogue_kernel(const float* __restrict__ agg,
                                                       const float* __restrict__ feat,
                                                       const float* __restrict__ d_inv,
                                                       const float* __restrict__ W,
                                                       const float* __restrict__ bias,
                                                       float* __restrict__ out) {
    __shared__ float aggL[64][65];
    __shared__ float wL[64][64];
    int t = threadIdx.x;
    int i0 = blockIdx.x * 64;
    int r = t >> 2;
    int cq = (t & 3) * 16;
    {
        const float* wp = W + r * 64 + cq;
        #pragma unroll
        for (int j = 0; j < 16; j += 4) {
            float4 v = *(const float4*)(wp + j);
            wL[r][cq + j + 0] = v.x; wL[r][cq + j + 1] = v.y;
            wL[r][cq + j + 2] = v.z; wL[r][cq + j + 3] = v.w;
        }
    }
    float dinv = d_inv[i0 + r];
    const float* fp = feat + (size_t)(i0 + r) * DF + cq;
    size_t base = (size_t)(i0 + r) * DF + cq;
    #pragma unroll
    for (int j = 0; j < 16; j += 4) {
        float4 a0 = *(const float4*)(agg + base + j);
        float4 a1 = *(const float4*)(agg + (size_t)N * DF + base + j);
        float4 a2 = *(const float4*)(agg + 2 * (size_t)N * DF + base + j);
        float4 a3 = *(const float4*)(agg + 3 * (size_t)N * DF + base + j);
        float4 fv = *(const float4*)(fp + j);
        aggL[r][cq + j + 0] = (a0.x + a1.x + a2.x + a3.x + fv.x * dinv) * dinv;
        aggL[r][cq + j + 1] = (a0.y + a1.y + a2.y + a3.y + fv.y * dinv) * dinv;
        aggL[r][cq + j + 2] = (a0.z + a1.z + a2.z + a3.z + fv.z * dinv) * dinv;
        aggL[r][cq + j + 3] = (a0.w + a1.w + a2.w + a3.w + fv.w * dinv) * dinv;
    }
    __syncthreads();
    int k = t & 63;
    int rg = t >> 6;
    float bk = bias[k];
    for (int it = 0; it < 16; ++it) {
        int rr = rg * 16 + it;
        float acc = bk;
        #pragma unroll
        for (int c = 0; c < 64; ++c) acc += aggL[rr][c] * wL[c][k];
        out[(size_t)(i0 + rr) * DF + k] = fmaxf(acc, 0.0f);
    }
}

extern "C" void kernel_launch(void* const* d_in, const int* in_sizes, int n_in,
                              void* d_out, int out_size, void* d_ws, size_t ws_size,
                              hipStream_t stream) {
    const float* A    = (const float*)d_in[0];
    const float* feat = (const float*)d_in[1];
    const float* W    = (const float*)d_in[2];
    const float* bias = (const float*)d_in[3];
    float* out = (float*)d_out;

    float* ws = (float*)d_ws;
    float* partial = ws;                                   // 64*N floats (4.2 MB)
    float* agg     = ws + (size_t)PROWS * N;               // KSPLIT*N*64 floats (16.8 MB)
    float* dinv    = agg + (size_t)KSPLIT * N * DF;        // N floats
    unsigned short* xsT = (unsigned short*)(dinv + N);     // 64*N bf16 (2.1 MB)

    colsum_kernel<<<dim3(16, 64), 256, 0, stream>>>(A, partial);
    prep_kernel<<<N / 64, 256, 0, stream>>>(feat, partial, dinv, xsT);
    gemm_kernel<<<(N / 64) * KSPLIT, 256, 0, stream>>>(A, xsT, agg);
    epilogue_kernel<<<N / 64, 256, 0, stream>>>(agg, feat, dinv, W, bias, out);
}

// Round 4
// 493.300 us; speedup vs baseline: 1.1343x; 1.1343x over previous
//
#include <hip/hip_runtime.h>
#include <hip/hip_bf16.h>
#include <cstdint>
#include <cstddef>

#define N 16384
#define DF 64

typedef __attribute__((ext_vector_type(8))) short short8;
typedef __attribute__((ext_vector_type(4))) float f32x4;

__device__ __forceinline__ unsigned short f2bf(float f) {
    union { float f; uint32_t u; } v; v.f = f;
    uint32_t u = v.u;
    uint32_t r = u + 0x7fffu + ((u >> 16) & 1u);  // RNE (data has no NaN/Inf)
    return (unsigned short)(r >> 16);
}

// ---------------- k1: partial column sums of A + bf16 convert ----------------
// grid (16, 64): blockIdx.x = 1024-col chunk, blockIdx.y = 256-row chunk
#define PROWS 64
__global__ __launch_bounds__(256) void colsum_convert_kernel(const float* __restrict__ A,
                                                             unsigned short* __restrict__ A16,
                                                             float* __restrict__ partial) {
    int t = threadIdx.x;
    int c0 = blockIdx.x * 1024 + t * 4;
    int r0 = blockIdx.y * 256;
    const float* p = A + (size_t)r0 * N + c0;
    unsigned short* q = A16 + (size_t)r0 * N + c0;
    float ax = 0.f, ay = 0.f, az = 0.f, aw = 0.f;
    #pragma unroll 4
    for (int r = 0; r < 256; ++r) {
        float4 v = *(const float4*)(p + (size_t)r * N);
        ax += v.x; ay += v.y; az += v.z; aw += v.w;
        ushort4 o;
        o.x = f2bf(v.x); o.y = f2bf(v.y); o.z = f2bf(v.z); o.w = f2bf(v.w);
        *(ushort4*)(q + (size_t)r * N) = o;
    }
    float4 o; o.x = ax; o.y = ay; o.z = az; o.w = aw;
    *(float4*)&partial[(size_t)blockIdx.y * N + c0] = o;
}

// ---------------- k2: reduce partials -> d_inv + xs^T (bf16, [64][N]) ----------------
__global__ __launch_bounds__(256) void prep_kernel(const float* __restrict__ feat,
                                                   const float* __restrict__ partial,
                                                   float* __restrict__ d_inv,
                                                   unsigned short* __restrict__ xsT) {
    __shared__ float tile[64][68];
    int t = threadIdx.x;
    int i0 = blockIdx.x * 64;
    int r = t >> 2;
    int q = t & 3;
    float s = 0.f;
    #pragma unroll
    for (int p = 0; p < 16; ++p)
        s += partial[(size_t)(q * 16 + p) * N + i0 + r];
    s += __shfl_xor(s, 1);
    s += __shfl_xor(s, 2);
    float dinv = 1.0f / (s + 1.0f);
    if (q == 0) d_inv[i0 + r] = dinv;

    int cq = q * 16;
    const float* fp = feat + (size_t)(i0 + r) * DF + cq;
    #pragma unroll
    for (int j = 0; j < 16; j += 4) {
        float4 v = *(const float4*)(fp + j);
        tile[r][cq + j + 0] = v.x * dinv;
        tile[r][cq + j + 1] = v.y * dinv;
        tile[r][cq + j + 2] = v.z * dinv;
        tile[r][cq + j + 3] = v.w * dinv;
    }
    __syncthreads();
    int c = t >> 2;
    int iq = (t & 3) * 16;
    short8 b0, b1;
    #pragma unroll
    for (int j = 0; j < 8; ++j) b0[j] = (short)f2bf(tile[iq + j][c]);
    #pragma unroll
    for (int j = 0; j < 8; ++j) b1[j] = (short)f2bf(tile[iq + 8 + j][c]);
    unsigned short* dst = xsT + (size_t)c * N + i0 + iq;
    *(short8*)(dst) = b0;
    *(short8*)(dst + 8) = b1;
}

// ---------------- k3: slab[ks] = A16[:, chunk] @ xs[chunk]  (bf16 MFMA, LDS-staged B) ----------------
#define KSPLIT 4
#define KCHUNK (N / KSPLIT)  // 4096
#define BK 256
#define LDK 264              // padded LDS stride (elements)

__global__ __launch_bounds__(256) void gemm_kernel(const unsigned short* __restrict__ A16,
                                                   const unsigned short* __restrict__ xsT,
                                                   float* __restrict__ agg) {
    __shared__ __align__(16) unsigned short xtile[64 * LDK];
    int t = threadIdx.x;
    int bid = blockIdx.x;
    int mb = bid >> 2;       // 0..255
    int ks = bid & 3;        // 0..3
    int m0 = mb * 64;
    int k0 = ks * KCHUNK;
    int w = t >> 6;          // wave 0..3 -> rows [m0+16w, +16)
    int l = t & 63;
    int row = m0 + w * 16 + (l & 15);
    int kofs = (l >> 4) * 8;

    const unsigned short* arow = A16 + (size_t)row * N + k0 + kofs;

    f32x4 acc[4] = {};

    for (int kt = 0; kt < KCHUNK; kt += BK) {
        __syncthreads();  // previous tile fully consumed
        // stage xs^T tile: 64 cols x BK k  (2048 x 16B chunks / 256 threads)
        #pragma unroll
        for (int i = 0; i < 8; ++i) {
            int ch = t + i * 256;
            int c = ch >> 5;
            int ko = (ch & 31) * 8;
            *(short8*)&xtile[c * LDK + ko] =
                *(const short8*)&xsT[(size_t)c * N + k0 + kt + ko];
        }
        __syncthreads();
        #pragma unroll
        for (int kk = 0; kk < BK; kk += 32) {
            short8 af = *(const short8*)(arow + kt + kk);
            #pragma unroll
            for (int ct = 0; ct < 4; ++ct) {
                short8 bf = *(const short8*)&xtile[(ct * 16 + (l & 15)) * LDK + kk + kofs];
                acc[ct] = __builtin_amdgcn_mfma_f32_16x16x32_bf16(af, bf, acc[ct], 0, 0, 0);
            }
        }
    }
    // C/D layout: col = lane&15, row_in_tile = (lane>>4)*4 + reg
    float* slab = agg + (size_t)ks * N * DF;
    int crow = m0 + w * 16 + (l >> 4) * 4;
    int ccol = l & 15;
    #pragma unroll
    for (int ct = 0; ct < 4; ++ct) {
        #pragma unroll
        for (int q = 0; q < 4; ++q)
            slab[(size_t)(crow + q) * DF + ct * 16 + ccol] = acc[ct][q];
    }
}

// ---------------- k4: out = relu(((sum slabs + f*dinv)*dinv) @ W + bias) ----------------
__global__ __launch_bounds__(256) void epilogue_kernel(const float* __restrict__ agg,
                                                       const float* __restrict__ feat,
                                                       const float* __restrict__ d_inv,
                                                       const float* __restrict__ W,
                                                       const float* __restrict__ bias,
                                                       float* __restrict__ out) {
    __shared__ float aggL[64][65];
    __shared__ float wL[64][64];
    int t = threadIdx.x;
    int i0 = blockIdx.x * 64;
    int r = t >> 2;
    int cq = (t & 3) * 16;
    {
        const float* wp = W + r * 64 + cq;
        #pragma unroll
        for (int j = 0; j < 16; j += 4) {
            float4 v = *(const float4*)(wp + j);
            wL[r][cq + j + 0] = v.x; wL[r][cq + j + 1] = v.y;
            wL[r][cq + j + 2] = v.z; wL[r][cq + j + 3] = v.w;
        }
    }
    float dinv = d_inv[i0 + r];
    const float* fp = feat + (size_t)(i0 + r) * DF + cq;
    size_t base = (size_t)(i0 + r) * DF + cq;
    #pragma unroll
    for (int j = 0; j < 16; j += 4) {
        float4 a0 = *(const float4*)(agg + base + j);
        float4 a1 = *(const float4*)(agg + (size_t)N * DF + base + j);
        float4 a2 = *(const float4*)(agg + 2 * (size_t)N * DF + base + j);
        float4 a3 = *(const float4*)(agg + 3 * (size_t)N * DF + base + j);
        float4 fv = *(const float4*)(fp + j);
        aggL[r][cq + j + 0] = (a0.x + a1.x + a2.x + a3.x + fv.x * dinv) * dinv;
        aggL[r][cq + j + 1] = (a0.y + a1.y + a2.y + a3.y + fv.y * dinv) * dinv;
        aggL[r][cq + j + 2] = (a0.z + a1.z + a2.z + a3.z + fv.z * dinv) * dinv;
        aggL[r][cq + j + 3] = (a0.w + a1.w + a2.w + a3.w + fv.w * dinv) * dinv;
    }
    __syncthreads();
    int k = t & 63;
    int rg = t >> 6;
    float bk = bias[k];
    for (int it = 0; it < 16; ++it) {
        int rr = rg * 16 + it;
        float acc = bk;
        #pragma unroll
        for (int c = 0; c < 64; ++c) acc += aggL[rr][c] * wL[c][k];
        out[(size_t)(i0 + rr) * DF + k] = fmaxf(acc, 0.0f);
    }
}

extern "C" void kernel_launch(void* const* d_in, const int* in_sizes, int n_in,
                              void* d_out, int out_size, void* d_ws, size_t ws_size,
                              hipStream_t stream) {
    const float* A    = (const float*)d_in[0];
    const float* feat = (const float*)d_in[1];
    const float* W    = (const float*)d_in[2];
    const float* bias = (const float*)d_in[3];
    float* out = (float*)d_out;

    unsigned short* A16 = (unsigned short*)d_ws;                  // N*N bf16 (512 MiB)
    float* partial = (float*)(A16 + (size_t)N * N);               // 64*N floats (4.2 MB)
    float* agg     = partial + (size_t)PROWS * N;                 // KSPLIT*N*64 floats (16.8 MB)
    float* dinv    = agg + (size_t)KSPLIT * N * DF;               // N floats
    unsigned short* xsT = (unsigned short*)(dinv + N);            // 64*N bf16 (2.1 MB)

    colsum_convert_kernel<<<dim3(16, 64), 256, 0, stream>>>(A, A16, partial);
    prep_kernel<<<N / 64, 256, 0, stream>>>(feat, partial, dinv, xsT);
    gemm_kernel<<<(N / 64) * KSPLIT, 256, 0, stream>>>(A16, xsT, agg);
    epilogue_kernel<<<N / 64, 256, 0, stream>>>(agg, feat, dinv, W, bias, out);
}

// Round 5
// 430.863 us; speedup vs baseline: 1.2986x; 1.1449x over previous
//
#include <hip/hip_runtime.h>
#include <hip/hip_bf16.h>
#include <cstdint>
#include <cstddef>

#define N 16384
#define DF 64

typedef __attribute__((ext_vector_type(8))) short short8;
typedef __attribute__((ext_vector_type(4))) float f32x4;

__device__ __forceinline__ unsigned short f2bf(float f) {
    union { float f; uint32_t u; } v; v.f = f;
    uint32_t u = v.u;
    uint32_t r = u + 0x7fffu + ((u >> 16) & 1u);  // RNE (data has no NaN/Inf)
    return (unsigned short)(r >> 16);
}

// ---------------- k1: partial column sums of A (race-free) ----------------
// grid (16, 64): blockIdx.x = 1024-col chunk, blockIdx.y = 256-row chunk
#define PROWS 64
__global__ __launch_bounds__(256) void colsum_kernel(const float* __restrict__ A,
                                                     float* __restrict__ partial) {
    int t = threadIdx.x;
    int c0 = blockIdx.x * 1024 + t * 4;
    int r0 = blockIdx.y * 256;
    const float* p = A + (size_t)r0 * N + c0;
    float ax = 0.f, ay = 0.f, az = 0.f, aw = 0.f;
    #pragma unroll 8
    for (int r = 0; r < 256; ++r) {
        float4 v = *(const float4*)(p + (size_t)r * N);
        ax += v.x; ay += v.y; az += v.z; aw += v.w;
    }
    float4 o; o.x = ax; o.y = ay; o.z = az; o.w = aw;
    *(float4*)&partial[(size_t)blockIdx.y * N + c0] = o;
}

// ---------------- k2: reduce partials -> d_inv + xs^T (bf16, [64][N]) ----------------
__global__ __launch_bounds__(256) void prep_kernel(const float* __restrict__ feat,
                                                   const float* __restrict__ partial,
                                                   float* __restrict__ d_inv,
                                                   unsigned short* __restrict__ xsT) {
    __shared__ float tile[64][68];
    int t = threadIdx.x;
    int i0 = blockIdx.x * 64;
    int r = t >> 2;
    int q = t & 3;
    float s = 0.f;
    #pragma unroll
    for (int p = 0; p < 16; ++p)
        s += partial[(size_t)(q * 16 + p) * N + i0 + r];
    s += __shfl_xor(s, 1);
    s += __shfl_xor(s, 2);
    float dinv = 1.0f / (s + 1.0f);
    if (q == 0) d_inv[i0 + r] = dinv;

    int cq = q * 16;
    const float* fp = feat + (size_t)(i0 + r) * DF + cq;
    #pragma unroll
    for (int j = 0; j < 16; j += 4) {
        float4 v = *(const float4*)(fp + j);
        tile[r][cq + j + 0] = v.x * dinv;
        tile[r][cq + j + 1] = v.y * dinv;
        tile[r][cq + j + 2] = v.z * dinv;
        tile[r][cq + j + 3] = v.w * dinv;
    }
    __syncthreads();
    int c = t >> 2;
    int iq = (t & 3) * 16;
    short8 b0, b1;
    #pragma unroll
    for (int j = 0; j < 8; ++j) b0[j] = (short)f2bf(tile[iq + j][c]);
    #pragma unroll
    for (int j = 0; j < 8; ++j) b1[j] = (short)f2bf(tile[iq + 8 + j][c]);
    unsigned short* dst = xsT + (size_t)c * N + i0 + iq;
    *(short8*)(dst) = b0;
    *(short8*)(dst + 8) = b1;
}

// ---------------- k3: slab[ks] = A[:, chunk] @ xs[chunk]  (bf16 MFMA) ----------------
// KSPLIT=8, BK=128: LDS=17KB -> 8 blocks/CU -> 32 waves/CU (max occupancy)
#define KSPLIT 8
#define KCHUNK (N / KSPLIT)  // 2048
#define BK 128
#define LDK 136              // padded LDS stride (elements)

__global__ __launch_bounds__(256, 8) void gemm_kernel(const float* __restrict__ A,
                                                      const unsigned short* __restrict__ xsT,
                                                      float* __restrict__ agg) {
    __shared__ __align__(16) unsigned short xtile[64 * LDK];
    int t = threadIdx.x;
    int bid = blockIdx.x;
    int mb = bid >> 3;       // 0..255
    int ks = bid & 7;        // 0..7
    int m0 = mb * 64;
    int k0 = ks * KCHUNK;
    int w = t >> 6;          // wave 0..3 -> rows [m0+16w, +16)
    int l = t & 63;
    int row = m0 + w * 16 + (l & 15);
    int kofs = (l >> 4) * 8;

    const float* arow = A + (size_t)row * N + k0 + kofs;

    f32x4 acc[4] = {};

    for (int kt = 0; kt < KCHUNK; kt += BK) {
        __syncthreads();  // previous tile fully consumed
        // stage xs^T tile: 64 cols x BK k (1024 x 16B granules / 256 threads = 4 each)
        #pragma unroll
        for (int i = 0; i < 4; ++i) {
            int ch = t + i * 256;
            int c = ch >> 4;           // 16 granules per row of 128 k
            int ko = (ch & 15) * 8;
            *(short8*)&xtile[c * LDK + ko] =
                *(const short8*)&xsT[(size_t)c * N + k0 + kt + ko];
        }
        __syncthreads();
        #pragma unroll
        for (int kk = 0; kk < BK; kk += 32) {
            float4 a0 = *(const float4*)(arow + kt + kk);
            float4 a1 = *(const float4*)(arow + kt + kk + 4);
            short8 af;
            af[0] = (short)f2bf(a0.x); af[1] = (short)f2bf(a0.y);
            af[2] = (short)f2bf(a0.z); af[3] = (short)f2bf(a0.w);
            af[4] = (short)f2bf(a1.x); af[5] = (short)f2bf(a1.y);
            af[6] = (short)f2bf(a1.z); af[7] = (short)f2bf(a1.w);
            #pragma unroll
            for (int ct = 0; ct < 4; ++ct) {
                short8 bf = *(const short8*)&xtile[(ct * 16 + (l & 15)) * LDK + kk + kofs];
                acc[ct] = __builtin_amdgcn_mfma_f32_16x16x32_bf16(af, bf, acc[ct], 0, 0, 0);
            }
        }
    }
    // C/D layout: col = lane&15, row_in_tile = (lane>>4)*4 + reg
    float* slab = agg + (size_t)ks * N * DF;
    int crow = m0 + w * 16 + (l >> 4) * 4;
    int ccol = l & 15;
    #pragma unroll
    for (int ct = 0; ct < 4; ++ct) {
        #pragma unroll
        for (int q = 0; q < 4; ++q)
            slab[(size_t)(crow + q) * DF + ct * 16 + ccol] = acc[ct][q];
    }
}

// ---------------- k4: out = relu(((sum slabs + f*dinv)*dinv) @ W + bias) ----------------
__global__ __launch_bounds__(256) void epilogue_kernel(const float* __restrict__ agg,
                                                       const float* __restrict__ feat,
                                                       const float* __restrict__ d_inv,
                                                       const float* __restrict__ W,
                                                       const float* __restrict__ bias,
                                                       float* __restrict__ out) {
    __shared__ float aggL[64][65];
    __shared__ float wL[64][64];
    int t = threadIdx.x;
    int i0 = blockIdx.x * 64;
    int r = t >> 2;
    int cq = (t & 3) * 16;
    {
        const float* wp = W + r * 64 + cq;
        #pragma unroll
        for (int j = 0; j < 16; j += 4) {
            float4 v = *(const float4*)(wp + j);
            wL[r][cq + j + 0] = v.x; wL[r][cq + j + 1] = v.y;
            wL[r][cq + j + 2] = v.z; wL[r][cq + j + 3] = v.w;
        }
    }
    float dinv = d_inv[i0 + r];
    const float* fp = feat + (size_t)(i0 + r) * DF + cq;
    size_t base = (size_t)(i0 + r) * DF + cq;
    #pragma unroll
    for (int j = 0; j < 16; j += 4) {
        float4 fv = *(const float4*)(fp + j);
        float sx = fv.x * dinv, sy = fv.y * dinv, sz = fv.z * dinv, sw = fv.w * dinv;
        #pragma unroll
        for (int sl = 0; sl < KSPLIT; ++sl) {
            float4 a = *(const float4*)(agg + (size_t)sl * N * DF + base + j);
            sx += a.x; sy += a.y; sz += a.z; sw += a.w;
        }
        aggL[r][cq + j + 0] = sx * dinv;
        aggL[r][cq + j + 1] = sy * dinv;
        aggL[r][cq + j + 2] = sz * dinv;
        aggL[r][cq + j + 3] = sw * dinv;
    }
    __syncthreads();
    int k = t & 63;
    int rg = t >> 6;
    float bk = bias[k];
    for (int it = 0; it < 16; ++it) {
        int rr = rg * 16 + it;
        float acc = bk;
        #pragma unroll
        for (int c = 0; c < 64; ++c) acc += aggL[rr][c] * wL[c][k];
        out[(size_t)(i0 + rr) * DF + k] = fmaxf(acc, 0.0f);
    }
}

extern "C" void kernel_launch(void* const* d_in, const int* in_sizes, int n_in,
                              void* d_out, int out_size, void* d_ws, size_t ws_size,
                              hipStream_t stream) {
    const float* A    = (const float*)d_in[0];
    const float* feat = (const float*)d_in[1];
    const float* W    = (const float*)d_in[2];
    const float* bias = (const float*)d_in[3];
    float* out = (float*)d_out;

    float* ws = (float*)d_ws;
    float* partial = ws;                                   // 64*N floats (4.2 MB)
    float* agg     = ws + (size_t)PROWS * N;               // KSPLIT*N*64 floats (33.6 MB)
    float* dinv    = agg + (size_t)KSPLIT * N * DF;        // N floats
    unsigned short* xsT = (unsigned short*)(dinv + N);     // 64*N bf16 (2.1 MB)

    colsum_kernel<<<dim3(16, 64), 256, 0, stream>>>(A, partial);
    prep_kernel<<<N / 64, 256, 0, stream>>>(feat, partial, dinv, xsT);
    gemm_kernel<<<(N / 64) * KSPLIT, 256, 0, stream>>>(A, xsT, agg);
    epilogue_kernel<<<N / 64, 256, 0, stream>>>(agg, feat, dinv, W, bias, out);
}